// Round 3
// baseline (405.086 us; speedup 1.0000x reference)
//
#include <hip/hip_runtime.h>
#include <hip/hip_bf16.h>

typedef __bf16 bf16_t;
typedef __attribute__((ext_vector_type(8))) __bf16 bf16x8;
typedef __attribute__((ext_vector_type(4))) __bf16 bf16x4;
typedef __attribute__((ext_vector_type(4))) float floatx4;
typedef __attribute__((ext_vector_type(4))) int intx4;

#define NN 8192
#define FIN 256
#define FOUT 64
#define GAT_ALPHA 0.2f
#define NSLICE 16
#define JS (NN / NSLICE)    // 512 j per slice
#define NCH (JS / 64)       // 8 chunks of 64 j

// global_load_lds: wave-uniform LDS base, per-lane global src, 16B/lane
typedef const __attribute__((address_space(1))) void gv_t;
typedef __attribute__((address_space(3))) void lv_t;
#define GLOAD16(gp, lp) \
    __builtin_amdgcn_global_load_lds((gv_t*)(gp), (lv_t*)(lp), 16, 0, 0)

// ---------------------------------------------------------------------------
// Kernel A: h = input @ W (fp32 in -> bf16 MFMA), store hT (bf16 [64][8192])
// and per-row scalars s1,s2 (fp32), E=exp(s), F=exp(0.2 s).  (unchanged)
// ---------------------------------------------------------------------------
__global__ __launch_bounds__(256) void gat_h_kernel(
    const float* __restrict__ input,    // [8192][256] fp32
    const float* __restrict__ W,        // [256][64] fp32
    const float* __restrict__ a,        // [128] fp32
    bf16_t* __restrict__ hT,            // [64][8192] bf16 (internal)
    float* __restrict__ s1g, float* __restrict__ e1g, float* __restrict__ f1g,
    float* __restrict__ s2g, float* __restrict__ e2g, float* __restrict__ f2g)
{
    alignas(16) __shared__ bf16_t in_lds[32][264];  // input tile, K contiguous
    alignas(16) __shared__ bf16_t wt_lds[64][264];  // W transposed [f][k]
    __shared__ float h_lds[32][65];                 // h tile fp32 for s1/s2

    const int t  = threadIdx.x;
    const int i0 = blockIdx.x * 32;

    #pragma unroll
    for (int v = 0; v < 8; v++) {
        int u  = v * 256 + t;
        int i  = u >> 6;
        int k4 = (u & 63) * 4;
        floatx4 x = *(const floatx4*)(input + (size_t)(i0 + i) * FIN + k4);
        bf16x4 b;
        #pragma unroll
        for (int e = 0; e < 4; e++) b[e] = (bf16_t)x[e];
        *(bf16x4*)(&in_lds[i][k4]) = b;
    }
    #pragma unroll
    for (int v = 0; v < 16; v++) {
        int u  = v * 256 + t;
        int k  = u >> 4;
        int f4 = (u & 15) * 4;
        floatx4 wv = *(const floatx4*)(W + k * FOUT + f4);
        #pragma unroll
        for (int e = 0; e < 4; e++) wt_lds[f4 + e][k] = (bf16_t)wv[e];
    }
    __syncthreads();

    const int wave = t >> 6;
    const int lane = t & 63;
    const int i16  = (wave & 1) * 16;
    const int f32  = (wave >> 1) * 32;
    const int lm   = lane & 15;
    const int lq   = lane >> 4;

    floatx4 acc0 = {0.f, 0.f, 0.f, 0.f};
    floatx4 acc1 = {0.f, 0.f, 0.f, 0.f};
    #pragma unroll
    for (int ks = 0; ks < 8; ks++) {
        int ko = ks * 32 + lq * 8;
        bf16x8 af = *(const bf16x8*)(&in_lds[i16 + lm][ko]);
        bf16x8 b0 = *(const bf16x8*)(&wt_lds[f32 + lm][ko]);
        bf16x8 b1 = *(const bf16x8*)(&wt_lds[f32 + 16 + lm][ko]);
        acc0 = __builtin_amdgcn_mfma_f32_16x16x32_bf16(af, b0, acc0, 0, 0, 0);
        acc1 = __builtin_amdgcn_mfma_f32_16x16x32_bf16(af, b1, acc1, 0, 0, 0);
    }

    #pragma unroll
    for (int c = 0; c < 2; c++) {
        floatx4 acc = c ? acc1 : acc0;
        int f  = f32 + c * 16 + lm;
        int ib = i0 + i16 + lq * 4;
        bf16x4 hp;
        #pragma unroll
        for (int r = 0; r < 4; r++) hp[r] = (bf16_t)acc[r];
        *(bf16x4*)(hT + (size_t)f * NN + ib) = hp;
    }
    #pragma unroll
    for (int c = 0; c < 2; c++) {
        floatx4 acc = c ? acc1 : acc0;
        #pragma unroll
        for (int r = 0; r < 4; r++)
            h_lds[i16 + lq * 4 + r][f32 + c * 16 + lm] = acc[r];
    }
    __syncthreads();

    if (t < 64) {
        int r   = t & 31;
        int sel = t >> 5;
        const float* av = a + sel * FOUT;
        float s = 0.f;
        #pragma unroll 8
        for (int f = 0; f < FOUT; f++) s += h_lds[r][f] * av[f];
        int gi = i0 + r;
        float E = expf(s);
        float F = expf(GAT_ALPHA * s);
        if (sel == 0) { s1g[gi] = s; e1g[gi] = E; f1g[gi] = F; }
        else          { s2g[gi] = s; e2g[gi] = E; f2g[gi] = F; }
    }
}

// ---------------------------------------------------------------------------
// Kernel B: pipelined LDS attention+aggregation, 3-buffer / 1-barrier.
//  - block = 256 thr (4 waves), 32 i-rows, JS=512 j-slice, chunks of 64 j
//  - TRIPLE-buffered global_load_lds staging of adj[32][64] + hT[64][64]
//  - per-chunk schedule: vmcnt(4) -> s_barrier -> stage(c+2) -> compute(c).
//    buf (c+2)%3 == buf (c-1)%3 is free once all waves pass barrier c, so
//    ONE barrier per chunk and every stage has ~2 chunk-times of latency
//    cover (>= 900cyc HBM latency). Counted vmcnt keeps next chunk's loads
//    in flight across the barrier (no vmcnt(0) drain in main loop).
//  - XOR-16B-granule swizzle on global SOURCE (linear LDS dest, rule #21)
//  - w computed in-register straight into A-fragment layout
//  - rowsum via MFMA against all-ones B fragment (wf==0 waves only)
// LDS = 52 KB -> 3 blocks/CU, 12 waves/CU.
// ---------------------------------------------------------------------------
__global__ __launch_bounds__(256, 3) void gat_att_kernel(
    const int* __restrict__ adj,        // [8192][8192] int32
    const bf16_t* __restrict__ hT,      // [64][8192] bf16
    const float* __restrict__ e1g, const float* __restrict__ f1g,
    const float* __restrict__ e2g, const float* __restrict__ f2g,
    float* __restrict__ pacc,           // [NSLICE][8192][64] fp32
    float* __restrict__ prs)            // [NSLICE][8192] fp32
{
    __shared__ int    adjL[3][32][64];            // 24 KB (swizzled layout)
    alignas(16) __shared__ bf16_t htL[3][64][64]; // 24 KB (swizzled layout)
    __shared__ float  e2l[JS], f2l[JS];           // 4 KB

    const int t     = threadIdx.x;
    const int i0    = blockIdx.x * 32;
    const int slice = blockIdx.y;
    const int jbase = slice * JS;

    const int wave = t >> 6;
    const int lane = t & 63;
    const int lm   = lane & 15;
    const int lq   = lane >> 4;
    const int wm   = wave & 1;          // i-tile 0/1
    const int wf   = wave >> 1;         // f-half 0/1
    const int xm   = lm & 7;            // XOR swizzle mask (= row&7 = f&7)

    // ---- prologue: stage e2/f2 slice (1 instr/wave, linear) ----
    {
        const float* src = (wave & 2) ? f2g : e2g;
        float*       dst = (wave & 2) ? f2l : e2l;
        int off = (wave & 1) * 256;
        GLOAD16(src + jbase + off + lane * 4, dst + off);
    }

    // ---- staging: 4 global_load_lds per wave per chunk ----
    auto stage = [&](int b, int c) {
        const int jg = jbase + c * 64;
        #pragma unroll
        for (int h = 0; h < 2; h++) {          // adj rows wave*8 .. +7
            int r0 = wave * 8 + h * 4;
            int i  = r0 + (lane >> 4);
            int gl = (lane & 15) ^ (i & 7);    // inverse swizzle on source
            GLOAD16(adj + (size_t)(i0 + i) * NN + jg + gl * 4,
                    &adjL[b][r0][0]);
        }
        #pragma unroll
        for (int h = 0; h < 2; h++) {          // hT rows wave*16 .. +15
            int f0 = wave * 16 + h * 8;
            int f  = f0 + (lane >> 3);
            int gl = (lane & 7) ^ (f & 7);
            GLOAD16(hT + (size_t)f * NN + jg + gl * 8,
                    &htL[b][f0][0]);
        }
    };

    stage(0, 0);
    stage(1, 1);

    const int   row = i0 + wm * 16 + lm;
    const float E1  = e1g[row];
    const float F1  = f1g[row];

    floatx4 acc0 = {0.f,0.f,0.f,0.f}, acc1 = {0.f,0.f,0.f,0.f};
    floatx4 accR = {0.f,0.f,0.f,0.f};
    bf16x8 ones;
    #pragma unroll
    for (int e = 0; e < 8; e++) ones[e] = (bf16_t)1.0f;

    #pragma unroll
    for (int c = 0; c < NCH; c++) {
        const int b = c % 3;
        // wait own chunk-c loads; chunk c+1's 4 stay in flight
        if (c + 1 < NCH) asm volatile("s_waitcnt vmcnt(4)" ::: "memory");
        else             asm volatile("s_waitcnt vmcnt(0)" ::: "memory");
        __builtin_amdgcn_s_barrier();   // all waves' chunk c visible; all
        asm volatile("" ::: "memory");  // waves finished chunk c-1 compute
        // buf (c+2)%3 == buf (c-1)%3: free now -> issue 2 chunks early
        if (c + 2 < NCH) stage((c + 2) % 3, c + 2);

        const char* aB = (const char*)&adjL[b][wm * 16 + lm][0];
        const char* hB = (const char*)&htL[b][0][0];
        const int   j0 = c * 64;
        #pragma unroll
        for (int ks = 0; ks < 2; ks++) {
            intx4 a0 = *(const intx4*)(aB + (((ks * 8 + lq * 2 + 0) ^ xm) << 4));
            intx4 a1 = *(const intx4*)(aB + (((ks * 8 + lq * 2 + 1) ^ xm) << 4));
            int jo = j0 + ks * 32 + lq * 8;
            floatx4 e2a = *(const floatx4*)(&e2l[jo]);
            floatx4 e2b = *(const floatx4*)(&e2l[jo + 4]);
            floatx4 f2a = *(const floatx4*)(&f2l[jo]);
            floatx4 f2b = *(const floatx4*)(&f2l[jo + 4]);
            bf16x8 frag;
            #pragma unroll
            for (int e = 0; e < 4; e++) {
                float w0 = fmaxf(E1 * e2a[e], F1 * f2a[e]);
                frag[e]     = (bf16_t)((a0[e] > 0) ? w0 : 0.f);
                float w1 = fmaxf(E1 * e2b[e], F1 * f2b[e]);
                frag[e + 4] = (bf16_t)((a1[e] > 0) ? w1 : 0.f);
            }
            int gh = ((ks * 4 + lq) ^ xm) << 4;
            bf16x8 b0 = *(const bf16x8*)(hB + (wf * 32 + lm) * 128 + gh);
            bf16x8 b1 = *(const bf16x8*)(hB + (wf * 32 + 16 + lm) * 128 + gh);
            acc0 = __builtin_amdgcn_mfma_f32_16x16x32_bf16(frag, b0, acc0, 0, 0, 0);
            acc1 = __builtin_amdgcn_mfma_f32_16x16x32_bf16(frag, b1, acc1, 0, 0, 0);
            if (wf == 0)
                accR = __builtin_amdgcn_mfma_f32_16x16x32_bf16(frag, ones, accR, 0, 0, 0);
        }
        asm volatile("" ::: "memory");
    }

    // ---- rowsum write (wf==0 waves; all lm lanes identical -> lm==0) ----
    if (wf == 0 && lm == 0) {
        #pragma unroll
        for (int r = 0; r < 4; r++)
            prs[(size_t)slice * NN + i0 + wm * 16 + lq * 4 + r] = accR[r];
    }

    // ---- partial acc write: D layout col = lm, row = lq*4+r ----
    float* pa = pacc + (size_t)slice * NN * FOUT
                     + (size_t)(i0 + wm * 16) * FOUT;
    #pragma unroll
    for (int ft = 0; ft < 2; ft++) {
        floatx4 acc = ft ? acc1 : acc0;
        #pragma unroll
        for (int r = 0; r < 4; r++)
            pa[(size_t)(lq * 4 + r) * FOUT + wf * 32 + ft * 16 + lm] = acc[r];
    }
}

// ---------------------------------------------------------------------------
// Kernel C: combine NSLICE partials, normalize, ELU, store fp32 output.
// ---------------------------------------------------------------------------
__global__ __launch_bounds__(256) void gat_combine_kernel(
    const float* __restrict__ pacc,     // [NSLICE][8192][64]
    const float* __restrict__ prs,      // [NSLICE][8192]
    float* __restrict__ out)            // [8192][64]
{
    int idx = blockIdx.x * 256 + threadIdx.x;
    int i   = idx >> 4;
    floatx4 s = {0.f, 0.f, 0.f, 0.f};
    float rs  = 0.f;
    #pragma unroll
    for (int p = 0; p < NSLICE; p++) {
        floatx4 v = *(const floatx4*)(pacc + (size_t)p * NN * FOUT + (size_t)idx * 4);
        s += v;
        rs += prs[p * NN + i];
    }
    float rinv = (rs > 0.f) ? 1.0f / rs : 0.f;
    floatx4 r;
    #pragma unroll
    for (int e = 0; e < 4; e++) {
        float x = s[e] * rinv;
        r[e] = (x > 0.f) ? x : (expf(x) - 1.0f);
    }
    *(floatx4*)(out + (size_t)idx * 4) = r;
}

// ---------------------------------------------------------------------------
extern "C" void kernel_launch(void* const* d_in, const int* in_sizes, int n_in,
                              void* d_out, int out_size, void* d_ws, size_t ws_size,
                              hipStream_t stream) {
    const float* input = (const float*)d_in[0];     // [8192][256] fp32
    const int*   adj   = (const int*)d_in[1];       // [8192][8192] int32
    const float* W     = (const float*)d_in[2];     // [256][64] fp32
    const float* a     = (const float*)d_in[3];     // [128] fp32
    float*       out   = (float*)d_out;             // [8192][64] fp32

    char* ws = (char*)d_ws;
    bf16_t* hT  = (bf16_t*)ws;                      // 64*8192*2 = 1 MiB
    float*  s1g = (float*)(ws + (1 << 20));
    float*  e1g = s1g + NN;
    float*  f1g = e1g + NN;
    float*  s2g = f1g + NN;
    float*  e2g = s2g + NN;
    float*  f2g = e2g + NN;
    float*  pacc = f2g + NN;                        // NSLICE*8192*64 fp32 = 32 MiB
    float*  prs  = pacc + (size_t)NSLICE * NN * FOUT;  // NSLICE*8192 fp32

    gat_h_kernel<<<NN / 32, 256, 0, stream>>>(input, W, a, hT,
                                              s1g, e1g, f1g, s2g, e2g, f2g);
    dim3 gridB(NN / 32, NSLICE);
    gat_att_kernel<<<gridB, 256, 0, stream>>>(adj, hT, e1g, f1g, e2g, f2g,
                                              pacc, prs);
    gat_combine_kernel<<<NN * FOUT / 4 / 256, 256, 0, stream>>>(pacc, prs, out);
}

// Round 4
// 393.102 us; speedup vs baseline: 1.0305x; 1.0305x over previous
//
#include <hip/hip_runtime.h>
#include <hip/hip_bf16.h>

typedef __bf16 bf16_t;
typedef __attribute__((ext_vector_type(8))) __bf16 bf16x8;
typedef __attribute__((ext_vector_type(4))) __bf16 bf16x4;
typedef __attribute__((ext_vector_type(4))) float floatx4;
typedef __attribute__((ext_vector_type(4))) int intx4;

#define NN 8192
#define FIN 256
#define FOUT 64
#define GAT_ALPHA 0.2f
#define NSLICE 4
#define JS (NN / NSLICE)     // 2048 j per slice
#define JCH 128              // j per chunk
#define NCH (JS / JCH)       // 16 chunks
#define IB 64                // i-rows per block

// global_load_lds: wave-uniform LDS base, per-lane global src, 16B/lane
typedef const __attribute__((address_space(1))) void gv_t;
typedef __attribute__((address_space(3))) void lv_t;
#define GLOAD16(gp, lp) \
    __builtin_amdgcn_global_load_lds((gv_t*)(gp), (lv_t*)(lp), 16, 0, 0)

// ---------------------------------------------------------------------------
// Kernel A: h = input @ W (fp32 in -> bf16 MFMA). Stores h in MFMA
// B-FRAGMENT layout hTf[jb][ft][lane][8]: element (jb,ft,lq,lm,e) =
// h[jb*32 + lq*8 + e][ft*16 + lm]. A wave's B-frag load in kernel B is then
// a single contiguous 1KB global read. Also emits per-row E=exp(s),
// F=exp(0.2 s) for both attention halves.
// ---------------------------------------------------------------------------
__global__ __launch_bounds__(256) void gat_h_kernel(
    const float* __restrict__ input,    // [8192][256] fp32
    const float* __restrict__ W,        // [256][64] fp32
    const float* __restrict__ a,        // [128] fp32
    bf16_t* __restrict__ hTf,           // [256][4][64][8] bf16 frag layout
    float* __restrict__ e1g, float* __restrict__ f1g,
    float* __restrict__ e2g, float* __restrict__ f2g)
{
    alignas(16) __shared__ bf16_t in_lds[32][264];  // input tile, K contiguous
    alignas(16) __shared__ bf16_t wt_lds[64][264];  // W transposed [f][k]
    __shared__ float h_lds[32][65];                 // h tile fp32 for s1/s2

    const int t  = threadIdx.x;
    const int i0 = blockIdx.x * 32;

    #pragma unroll
    for (int v = 0; v < 8; v++) {
        int u  = v * 256 + t;
        int i  = u >> 6;
        int k4 = (u & 63) * 4;
        floatx4 x = *(const floatx4*)(input + (size_t)(i0 + i) * FIN + k4);
        bf16x4 b;
        #pragma unroll
        for (int e = 0; e < 4; e++) b[e] = (bf16_t)x[e];
        *(bf16x4*)(&in_lds[i][k4]) = b;
    }
    #pragma unroll
    for (int v = 0; v < 16; v++) {
        int u  = v * 256 + t;
        int k  = u >> 4;
        int f4 = (u & 15) * 4;
        floatx4 wv = *(const floatx4*)(W + k * FOUT + f4);
        #pragma unroll
        for (int e = 0; e < 4; e++) wt_lds[f4 + e][k] = (bf16_t)wv[e];
    }
    __syncthreads();

    const int wave = t >> 6;
    const int lane = t & 63;
    const int i16  = (wave & 1) * 16;
    const int f32  = (wave >> 1) * 32;
    const int lm   = lane & 15;
    const int lq   = lane >> 4;

    floatx4 acc0 = {0.f, 0.f, 0.f, 0.f};
    floatx4 acc1 = {0.f, 0.f, 0.f, 0.f};
    #pragma unroll
    for (int ks = 0; ks < 8; ks++) {
        int ko = ks * 32 + lq * 8;
        bf16x8 af = *(const bf16x8*)(&in_lds[i16 + lm][ko]);
        bf16x8 b0 = *(const bf16x8*)(&wt_lds[f32 + lm][ko]);
        bf16x8 b1 = *(const bf16x8*)(&wt_lds[f32 + 16 + lm][ko]);
        acc0 = __builtin_amdgcn_mfma_f32_16x16x32_bf16(af, b0, acc0, 0, 0, 0);
        acc1 = __builtin_amdgcn_mfma_f32_16x16x32_bf16(af, b1, acc1, 0, 0, 0);
    }

    // store hTf fragment layout. Lane holds h[i0+i16+lq*4+r][f32+c*16+lm];
    // frag coords: jb=i0/32, ft=f32/16+c, lq'=(i16+lq*4)/8, e=(lq&1)*4+r.
    {
        const int jb  = i0 >> 5;
        const int lqp = (i16 >> 3) + (lq >> 1);
        const int e0  = (lq & 1) * 4;
        #pragma unroll
        for (int c = 0; c < 2; c++) {
            floatx4 acc = c ? acc1 : acc0;
            int ft = (f32 >> 4) + c;
            bf16x4 hp;
            #pragma unroll
            for (int r = 0; r < 4; r++) hp[r] = (bf16_t)acc[r];
            *(bf16x4*)(hTf + (size_t)(((jb * 4 + ft) * 64 + lqp * 16 + lm) * 8 + e0)) = hp;
        }
    }
    // fp32 h tile into LDS for s1/s2
    #pragma unroll
    for (int c = 0; c < 2; c++) {
        floatx4 acc = c ? acc1 : acc0;
        #pragma unroll
        for (int r = 0; r < 4; r++)
            h_lds[i16 + lq * 4 + r][f32 + c * 16 + lm] = acc[r];
    }
    __syncthreads();

    if (t < 64) {
        int r   = t & 31;
        int sel = t >> 5;
        const float* av = a + sel * FOUT;
        float s = 0.f;
        #pragma unroll 8
        for (int f = 0; f < FOUT; f++) s += h_lds[r][f] * av[f];
        int gi = i0 + r;
        float E = expf(s);
        float F = expf(GAT_ALPHA * s);
        if (sel == 0) { e1g[gi] = E; f1g[gi] = F; }
        else          { e2g[gi] = E; f2g[gi] = F; }
    }
}

// ---------------------------------------------------------------------------
// Kernel B: attention + aggregation.
//  - block: 4 waves, IB=64 i-rows, JS=2048 j-slice, chunks of JCH=128 j
//  - each wave owns its OWN 16 rows x all 4 f-tiles: frag computed ONCE
//    per adj element (halves VALU vs wm/wf-redundant layouts)
//  - adj staged to LDS as full-row 512B bursts (1KB contiguous per
//    global_load_lds over 2 rows), XOR-16B-granule swizzle on SOURCE
//    (linear LDS dest), double-buffered; counted vmcnt(8) keeps the next
//    chunk's 8 loads in flight across both barriers
//  - hT NOT staged: kernel A pre-wrote it in B-fragment order, so the
//    B-operand is a contiguous 1KB per-wave global load (L2-resident, 1MB)
//  - rowsum via 5th MFMA against all-ones B fragment
// LDS = 80 KB -> 2 blocks/CU; grid = 512 blocks = exactly 2 resident/CU.
// ---------------------------------------------------------------------------
__global__ __launch_bounds__(256, 2) void gat_att_kernel(
    const int* __restrict__ adj,        // [8192][8192] int32
    const bf16_t* __restrict__ hTf,     // [256][4][64][8] bf16 frag layout
    const float* __restrict__ e1g, const float* __restrict__ f1g,
    const float* __restrict__ e2g, const float* __restrict__ f2g,
    float* __restrict__ pacc,           // [NSLICE][8192][64] fp32
    float* __restrict__ prs)            // [NSLICE][8192] fp32
{
    __shared__ int   adjL[2][IB][JCH];   // 64 KB, XOR-swizzled granules
    __shared__ float e2l[JS], f2l[JS];   // 16 KB

    const int t     = threadIdx.x;
    const int i0    = blockIdx.x * IB;
    const int slice = blockIdx.y;
    const int jbase = slice * JS;

    const int wave = t >> 6;
    const int lane = t & 63;
    const int lm   = lane & 15;
    const int lq   = lane >> 4;

    // ---- prologue: stage e2/f2 slice (4 instr/wave, linear) ----
    {
        int o = wave * 512;
        GLOAD16(e2g + jbase + o + lane * 4,       e2l + o);
        GLOAD16(e2g + jbase + o + 256 + lane * 4, e2l + o + 256);
        GLOAD16(f2g + jbase + o + lane * 4,       f2l + o);
        GLOAD16(f2g + jbase + o + 256 + lane * 4, f2l + o + 256);
    }

    // ---- adj staging: 8 global_load_lds per wave per chunk, 2 rows each.
    // LDS linear; source granule pre-XORed so read-side XOR is bank-spread.
    auto stage = [&](int b, int c) {
        const int jg = jbase + c * JCH;
        #pragma unroll
        for (int h = 0; h < 8; h++) {
            int r0 = wave * 16 + h * 2;
            int r  = r0 + (lane >> 5);
            int g  = (lane & 31) ^ (r & 7);
            GLOAD16(adj + (size_t)(i0 + r) * NN + jg + g * 4, &adjL[b][r0][0]);
        }
    };

    stage(0, 0);

    const int   row = i0 + wave * 16 + lm;   // this lane's A-frag row
    const float E1  = e1g[row];
    const float F1  = f1g[row];

    floatx4 acc0 = {0.f,0.f,0.f,0.f}, acc1 = {0.f,0.f,0.f,0.f};
    floatx4 acc2 = {0.f,0.f,0.f,0.f}, acc3 = {0.f,0.f,0.f,0.f};
    floatx4 accR = {0.f,0.f,0.f,0.f};
    bf16x8 ones;
    #pragma unroll
    for (int e = 0; e < 8; e++) ones[e] = (bf16_t)1.0f;

    for (int c = 0; c < NCH; c++) {
        if (c + 1 < NCH) {
            stage((c + 1) & 1, c + 1);                    // buf (c-1) is free
            asm volatile("s_waitcnt vmcnt(8)" ::: "memory"); // own chunk-c done
        } else {
            asm volatile("s_waitcnt vmcnt(0)" ::: "memory");
        }
        __builtin_amdgcn_s_barrier();   // all waves' chunk c in LDS
        asm volatile("" ::: "memory");

        const char* aB = (const char*)&adjL[c & 1][wave * 16 + lm][0];
        #pragma unroll
        for (int ks = 0; ks < 4; ks++) {
            int g0 = ks * 8 + lq * 2;
            intx4 a0 = *(const intx4*)(aB + (((g0    ) ^ (lm & 7)) << 4));
            intx4 a1 = *(const intx4*)(aB + (((g0 + 1) ^ (lm & 7)) << 4));
            int jo = c * JCH + ks * 32 + lq * 8;
            floatx4 e2a = *(const floatx4*)(&e2l[jo]);
            floatx4 e2b = *(const floatx4*)(&e2l[jo + 4]);
            floatx4 f2a = *(const floatx4*)(&f2l[jo]);
            floatx4 f2b = *(const floatx4*)(&f2l[jo + 4]);
            bf16x8 frag;
            #pragma unroll
            for (int e = 0; e < 4; e++) {
                float w0 = fmaxf(E1 * e2a[e], F1 * f2a[e]);
                frag[e]     = (bf16_t)((a0[e] > 0) ? w0 : 0.f);
                float w1 = fmaxf(E1 * e2b[e], F1 * f2b[e]);
                frag[e + 4] = (bf16_t)((a1[e] > 0) ? w1 : 0.f);
            }
            // B-frags: contiguous 1KB per wave from frag-layout hT (L2-hot)
            const int jb = slice * (JS / 32) + c * 4 + ks;
            const bf16_t* hb = hTf + (size_t)jb * 2048 + (size_t)lane * 8;
            bf16x8 b0 = *(const bf16x8*)(hb);
            bf16x8 b1 = *(const bf16x8*)(hb + 512);
            bf16x8 b2 = *(const bf16x8*)(hb + 1024);
            bf16x8 b3 = *(const bf16x8*)(hb + 1536);
            acc0 = __builtin_amdgcn_mfma_f32_16x16x32_bf16(frag, b0, acc0, 0, 0, 0);
            acc1 = __builtin_amdgcn_mfma_f32_16x16x32_bf16(frag, b1, acc1, 0, 0, 0);
            acc2 = __builtin_amdgcn_mfma_f32_16x16x32_bf16(frag, b2, acc2, 0, 0, 0);
            acc3 = __builtin_amdgcn_mfma_f32_16x16x32_bf16(frag, b3, acc3, 0, 0, 0);
            accR = __builtin_amdgcn_mfma_f32_16x16x32_bf16(frag, ones, accR, 0, 0, 0);
        }

        asm volatile("" ::: "memory");
        __builtin_amdgcn_s_barrier();   // all waves done reading buf c&1
        asm volatile("" ::: "memory");
    }

    // ---- rowsum write: accR col-independent; lm==0 lanes write ----
    if (lm == 0) {
        #pragma unroll
        for (int r = 0; r < 4; r++)
            prs[(size_t)slice * NN + i0 + wave * 16 + lq * 4 + r] = accR[r];
    }

    // ---- partial acc write: D layout col = ft*16+lm, row = lq*4+r ----
    float* pa = pacc + (size_t)slice * NN * FOUT
                     + (size_t)(i0 + wave * 16) * FOUT;
    #pragma unroll
    for (int ft = 0; ft < 4; ft++) {
        floatx4 acc = (ft == 0) ? acc0 : (ft == 1) ? acc1
                    : (ft == 2) ? acc2 : acc3;
        #pragma unroll
        for (int r = 0; r < 4; r++)
            pa[(size_t)(lq * 4 + r) * FOUT + ft * 16 + lm] = acc[r];
    }
}

// ---------------------------------------------------------------------------
// Kernel C: combine NSLICE partials, normalize, ELU, store fp32 output.
// ---------------------------------------------------------------------------
__global__ __launch_bounds__(256) void gat_combine_kernel(
    const float* __restrict__ pacc,     // [NSLICE][8192][64]
    const float* __restrict__ prs,      // [NSLICE][8192]
    float* __restrict__ out)            // [8192][64]
{
    int idx = blockIdx.x * 256 + threadIdx.x;
    int i   = idx >> 4;
    floatx4 s = {0.f, 0.f, 0.f, 0.f};
    float rs  = 0.f;
    #pragma unroll
    for (int p = 0; p < NSLICE; p++) {
        floatx4 v = *(const floatx4*)(pacc + (size_t)p * NN * FOUT + (size_t)idx * 4);
        s += v;
        rs += prs[p * NN + i];
    }
    float rinv = (rs > 0.f) ? 1.0f / rs : 0.f;
    floatx4 r;
    #pragma unroll
    for (int e = 0; e < 4; e++) {
        float x = s[e] * rinv;
        r[e] = (x > 0.f) ? x : (expf(x) - 1.0f);
    }
    *(floatx4*)(out + (size_t)idx * 4) = r;
}

// ---------------------------------------------------------------------------
extern "C" void kernel_launch(void* const* d_in, const int* in_sizes, int n_in,
                              void* d_out, int out_size, void* d_ws, size_t ws_size,
                              hipStream_t stream) {
    const float* input = (const float*)d_in[0];     // [8192][256] fp32
    const int*   adj   = (const int*)d_in[1];       // [8192][8192] int32
    const float* W     = (const float*)d_in[2];     // [256][64] fp32
    const float* a     = (const float*)d_in[3];     // [128] fp32
    float*       out   = (float*)d_out;             // [8192][64] fp32

    char* ws = (char*)d_ws;
    bf16_t* hTf = (bf16_t*)ws;                      // 64*8192*2 = 1 MiB
    float*  e1g = (float*)(ws + (1 << 20));
    float*  f1g = e1g + NN;
    float*  e2g = f1g + NN;
    float*  f2g = e2g + NN;
    float*  pacc = f2g + NN;                        // NSLICE*8192*64 fp32 = 8 MiB
    float*  prs  = pacc + (size_t)NSLICE * NN * FOUT;  // NSLICE*8192 fp32

    gat_h_kernel<<<NN / 32, 256, 0, stream>>>(input, W, a, hTf,
                                              e1g, f1g, e2g, f2g);
    dim3 gridB(NN / IB, NSLICE);
    gat_att_kernel<<<gridB, 256, 0, stream>>>(adj, hTf, e1g, f1g, e2g, f2g,
                                              pacc, prs);
    gat_combine_kernel<<<NN * FOUT / 4 / 256, 256, 0, stream>>>(pacc, prs, out);
}